// Round 3
// baseline (1717.920 us; speedup 1.0000x reference)
//
#include <hip/hip_runtime.h>
#include <hip/hip_bf16.h>
#include <cmath>

#define N_S    2048
#define C_CLS  100
#define K_CL   4
#define A_DIM  128
#define LDSROW 132   // 132*4=528B row stride: 16B-aligned rows, breaks 32-bank row aliasing
#define NB     16    // GJ panel width
#define MAXPER 96    // max samples per class (mean 20.5, this is >15 sigma)

// ---------------------------------------------------------------------------
// Kernel 0: bucket samples by class (replaces the per-block label scan + 8KB LDS)
// ---------------------------------------------------------------------------
__global__ __launch_bounds__(256) void k_bucket(
    const int* __restrict__ labels, int* __restrict__ cntg, int* __restrict__ idxg)
{
    __shared__ int cntL[C_CLS];
    const int t = threadIdx.x;
    if (t < C_CLS) cntL[t] = 0;
    __syncthreads();
    for (int n = t; n < N_S; n += 256) {
        int c = labels[n];
        int slot = atomicAdd(&cntL[c], 1);
        if (slot < MAXPER) idxg[c * MAXPER + slot] = n;
    }
    __syncthreads();
    if (t < C_CLS) cntg[t] = min(cntL[t], MAXPER);
}

// ---------------------------------------------------------------------------
// Kernel 1: per (cl,k) block: blocked Gauss-Jordan inversion of sigma[cl,k] in
// LDS (NB=16 panels; diagonal block inverted in-register by wave 0), fused
// logdet, then per-sample quadratic form for samples of class cl:
//   score[n][k] = (x-mu)^T Sigma^{-1} (x-mu) + logdet
// argmax_k log_p == argmin_k score.
// ---------------------------------------------------------------------------
__global__ __launch_bounds__(256, 2) void k_invert_score(
    const float* __restrict__ sigma, const float* __restrict__ mu,
    const float* __restrict__ features, const int* __restrict__ cntg,
    const int* __restrict__ idxg, float* __restrict__ score)
{
    __shared__ __align__(16) float As[A_DIM * LDSROW];
    __shared__ float DinvS[NB * 17];    // 17-stride: conflict-free row reads
    __shared__ float ldS;

    const int tid  = threadIdx.x;
    const int bid  = blockIdx.x;        // cl*K + k
    const int cl   = bid >> 2;
    const int lane = tid & 63;
    const int wv   = tid >> 6;

    // ---- stage sigma (coalesced b128) ----
    const float4* src = (const float4*)(sigma + (size_t)bid * A_DIM * A_DIM);
    for (int e4 = tid; e4 < A_DIM * 32; e4 += 256) {
        int i = e4 >> 5, j4 = e4 & 31;
        *(float4*)&As[i * LDSROW + 4 * j4] = src[e4];
    }
    __syncthreads();

    // ---- blocked GJ: 8 panels of 16 ----
    float logdet = 0.0f;                 // valid in wave 0 only
    const int rg  = tid >> 3;            // row group 0..31 (rows 4rg..4rg+3)
    const int cgr = tid & 7;             // col group (4 j4 = 16 cols) in update

    for (int t = 0; t < 8; ++t) {
        const int p0 = NB * t;

        // (a) wave 0: invert 16x16 diagonal block in registers
        if (wv == 0) {
            const int r = lane >> 2, cg = lane & 3;
            float4 dv = *(const float4*)&As[(p0 + r) * LDSROW + p0 + 4 * cg];
            #pragma unroll
            for (int p = 0; p < NB; ++p) {
                const int sel = p & 3, pr4 = p >> 2;
                float te = (sel == 0) ? dv.x : (sel == 1) ? dv.y : (sel == 2) ? dv.z : dv.w;
                float piv = __shfl(te, (p << 2) | pr4, 64);
                float ip  = 1.0f / piv;
                logdet += __logf(piv);
                const int rowsrc = (p << 2) | cg;
                float4 prs;
                prs.x = __shfl(dv.x, rowsrc, 64) * ip;
                prs.y = __shfl(dv.y, rowsrc, 64) * ip;
                prs.z = __shfl(dv.z, rowsrc, 64) * ip;
                prs.w = __shfl(dv.w, rowsrc, 64) * ip;
                if (cg == pr4) (&prs.x)[sel] = ip;           // row p, col p -> 1/piv
                float f = __shfl(te, (lane & ~3) | pr4, 64); // my row's col-p value
                if (r == p) {
                    dv = prs;
                } else {
                    dv.x -= f * prs.x; dv.y -= f * prs.y;
                    dv.z -= f * prs.z; dv.w -= f * prs.w;
                    if (cg == pr4) (&dv.x)[sel] = -f * ip;   // col p: assign
                }
            }
            DinvS[r * 17 + 4 * cg + 0] = dv.x;
            DinvS[r * 17 + 4 * cg + 1] = dv.y;
            DinvS[r * 17 + 4 * cg + 2] = dv.z;
            DinvS[r * 17 + 4 * cg + 3] = dv.w;
        }
        __syncthreads();   // b1: Dinv ready

        // (b) all: preload Cold (my 4 rows x 16 panel cols) into registers
        const bool inPanelR = ((rg >> 2) == t);
        float cold[4][NB];
        if (!inPanelR) {
            #pragma unroll
            for (int ri = 0; ri < 4; ++ri)
                #pragma unroll
                for (int k4 = 0; k4 < 4; ++k4) {
                    float4 v = *(const float4*)&As[(4 * rg + ri) * LDSROW + p0 + 4 * k4];
                    cold[ri][4 * k4 + 0] = v.x; cold[ri][4 * k4 + 1] = v.y;
                    cold[ri][4 * k4 + 2] = v.z; cold[ri][4 * k4 + 3] = v.w;
                }
        }
        // (c) row panel in place: Rnew = Dinv * A[P, j not in P]; A[P,P] = Dinv
        if (tid < 224) {
            const int q = tid >> 3, rr = tid & 7;
            const int j4 = (q < 4 * t) ? q : q + 4;     // skip the 4 panel j4s
            float4 s[NB];
            #pragma unroll
            for (int k = 0; k < NB; ++k)
                s[k] = *(const float4*)&As[(p0 + k) * LDSROW + 4 * j4];
            float4 o0 = {0, 0, 0, 0}, o1 = {0, 0, 0, 0};
            #pragma unroll
            for (int k = 0; k < NB; ++k) {
                float a0 = DinvS[(2 * rr) * 17 + k];
                float a1 = DinvS[(2 * rr + 1) * 17 + k];
                o0.x += a0 * s[k].x; o0.y += a0 * s[k].y; o0.z += a0 * s[k].z; o0.w += a0 * s[k].w;
                o1.x += a1 * s[k].x; o1.y += a1 * s[k].y; o1.z += a1 * s[k].z; o1.w += a1 * s[k].w;
            }
            // same-wave (8 threads/j4) ordering: all loads precede these stores
            *(float4*)&As[(p0 + 2 * rr)     * LDSROW + 4 * j4] = o0;
            *(float4*)&As[(p0 + 2 * rr + 1) * LDSROW + 4 * j4] = o1;
        } else {
            const int t2 = tid - 224, rD = t2 >> 1, hf = t2 & 1;
            float4 w0, w1;
            w0.x = DinvS[rD * 17 + 8 * hf + 0]; w0.y = DinvS[rD * 17 + 8 * hf + 1];
            w0.z = DinvS[rD * 17 + 8 * hf + 2]; w0.w = DinvS[rD * 17 + 8 * hf + 3];
            w1.x = DinvS[rD * 17 + 8 * hf + 4]; w1.y = DinvS[rD * 17 + 8 * hf + 5];
            w1.z = DinvS[rD * 17 + 8 * hf + 6]; w1.w = DinvS[rD * 17 + 8 * hf + 7];
            *(float4*)&As[(p0 + rD) * LDSROW + p0 + 8 * hf]     = w0;
            *(float4*)&As[(p0 + rD) * LDSROW + p0 + 8 * hf + 4] = w1;
        }
        __syncthreads();   // b2: row panel final

        // (d) rank-16 update of all non-panel rows (4 rows x 16 cols per thread)
        if (!inPanelR) {
            const bool pcol = (cgr == t);   // my 4 j4s are exactly the panel cols iff cgr==t
            float4 acc[4][4];
            #pragma unroll
            for (int ri = 0; ri < 4; ++ri)
                #pragma unroll
                for (int jj = 0; jj < 4; ++jj)
                    acc[ri][jj] = pcol ? (float4){0, 0, 0, 0}
                        : *(const float4*)&As[(4 * rg + ri) * LDSROW + 4 * (4 * cgr + jj)];
            #pragma unroll
            for (int k = 0; k < NB; ++k) {
                float4 rn[4];
                #pragma unroll
                for (int jj = 0; jj < 4; ++jj)
                    rn[jj] = *(const float4*)&As[(p0 + k) * LDSROW + 4 * (4 * cgr + jj)];
                #pragma unroll
                for (int ri = 0; ri < 4; ++ri) {
                    const float cf = cold[ri][k];
                    #pragma unroll
                    for (int jj = 0; jj < 4; ++jj) {
                        acc[ri][jj].x -= cf * rn[jj].x; acc[ri][jj].y -= cf * rn[jj].y;
                        acc[ri][jj].z -= cf * rn[jj].z; acc[ri][jj].w -= cf * rn[jj].w;
                    }
                }
            }
            #pragma unroll
            for (int ri = 0; ri < 4; ++ri)
                #pragma unroll
                for (int jj = 0; jj < 4; ++jj)
                    *(float4*)&As[(4 * rg + ri) * LDSROW + 4 * (4 * cgr + jj)] = acc[ri][jj];
        }
        __syncthreads();   // b3: panel done
    }
    // As = Sigma^{-1}

    if (tid == 0) ldS = logdet;
    __syncthreads();
    const float ld = ldS;

    // ---- per-sample quadratic form (bucketed; one sample per wave) ----
    const float m0 = mu[(size_t)bid * A_DIM + lane];
    const float m1 = mu[(size_t)bid * A_DIM + 64 + lane];
    const int cnt = cntg[cl];
    for (int s = wv; s < cnt; s += 4) {
        const int n = idxg[cl * MAXPER + s];
        float d0 = features[(size_t)n * A_DIM + lane]      - m0;
        float d1 = features[(size_t)n * A_DIM + 64 + lane] - m1;
        float p0v = 0.f, p1v = 0.f;
        for (int i = 0; i < 64; ++i) {
            float b = __shfl(d0, i, 64);
            p0v += b * As[i * LDSROW + lane];
            p1v += b * As[i * LDSROW + 64 + lane];
        }
        for (int i = 0; i < 64; ++i) {
            float b = __shfl(d1, i, 64);
            p0v += b * As[(i + 64) * LDSROW + lane];
            p1v += b * As[(i + 64) * LDSROW + 64 + lane];
        }
        float q = d0 * p0v + d1 * p1v;
        #pragma unroll
        for (int off = 32; off; off >>= 1) q += __shfl_xor(q, off, 64);
        if (lane == 0) score[n * K_CL + (bid & 3)] = q + ld;
    }
}

// ---------------------------------------------------------------------------
// Kernel 2: per (cl,k): gdiag[c]=W[c] S W[c]^T, gcol[c]=W[c] S W[cl]^T
// (4 rows batched per pass to amortize LDS reads of S)
// ---------------------------------------------------------------------------
__global__ __launch_bounds__(256, 2) void k_gprep(
    const float* __restrict__ sigma, const float* __restrict__ weight,
    float* __restrict__ gdiag, float* __restrict__ gcol)
{
    __shared__ __align__(16) float Ss[A_DIM * A_DIM];
    const int tid = threadIdx.x, bid = blockIdx.x;
    const int cl  = bid >> 2;
    const int lane = tid & 63, wv = tid >> 6;

    const float4* src = (const float4*)(sigma + (size_t)bid * A_DIM * A_DIM);
    for (int e4 = tid; e4 < A_DIM * 32; e4 += 256) {
        int i = e4 >> 5, j4 = e4 & 31;
        *(float4*)&Ss[i * A_DIM + 4 * j4] = src[e4];
    }
    __syncthreads();

    const float wc0 = weight[cl * A_DIM + lane];
    const float wc1 = weight[cl * A_DIM + 64 + lane];
    const int cbeg = wv * 25, cend = cbeg + 25;
    for (int c0 = cbeg; c0 < cend; c0 += 4) {
        const int nc = min(4, cend - c0);
        float r0[4], r1[4], h0[4], h1[4];
        #pragma unroll
        for (int cc = 0; cc < 4; ++cc) {
            int c = c0 + ((cc < nc) ? cc : 0);
            r0[cc] = weight[c * A_DIM + lane];
            r1[cc] = weight[c * A_DIM + 64 + lane];
            h0[cc] = 0.f; h1[cc] = 0.f;
        }
        for (int i = 0; i < 64; ++i) {
            float s0 = Ss[i * A_DIM + lane], s1 = Ss[i * A_DIM + 64 + lane];
            #pragma unroll
            for (int cc = 0; cc < 4; ++cc) {
                float b = __shfl(r0[cc], i, 64);
                h0[cc] += b * s0; h1[cc] += b * s1;
            }
        }
        for (int i = 0; i < 64; ++i) {
            float s0 = Ss[(64 + i) * A_DIM + lane], s1 = Ss[(64 + i) * A_DIM + 64 + lane];
            #pragma unroll
            for (int cc = 0; cc < 4; ++cc) {
                float b = __shfl(r1[cc], i, 64);
                h0[cc] += b * s0; h1[cc] += b * s1;
            }
        }
        #pragma unroll
        for (int cc = 0; cc < 4; ++cc) {
            if (cc >= nc) break;
            float pd = h0[cc] * r0[cc] + h1[cc] * r1[cc];
            float pc = h0[cc] * wc0 + h1[cc] * wc1;
            #pragma unroll
            for (int off = 32; off; off >>= 1) {
                pd += __shfl_xor(pd, off, 64);
                pc += __shfl_xor(pc, off, 64);
            }
            if (lane == 0) {
                gdiag[bid * C_CLS + c0 + cc] = pd;
                gcol [bid * C_CLS + c0 + cc] = pc;
            }
        }
    }
}

// ---------------------------------------------------------------------------
// Kernel 3 (fused fc + final): per sample: y = xW^T+b (written out), kstar =
// argmin_k score, aug = y + 0.5*ratio*(gdiag - 2 gcol + gll), log-softmax, loss.
// ---------------------------------------------------------------------------
__global__ __launch_bounds__(128) void k_out(
    const float* __restrict__ features, const float* __restrict__ weight,
    const float* __restrict__ bias, const int* __restrict__ labels,
    const float* __restrict__ score, const float* __restrict__ gdiag,
    const float* __restrict__ gcol, const float* __restrict__ ratio_p,
    float* __restrict__ y, float* __restrict__ loss)
{
    __shared__ __align__(16) float xs[A_DIM];
    __shared__ float red[2], red2[2], acl_s;
    const int n = blockIdx.x, t = threadIdx.x;
    xs[t] = features[(size_t)n * A_DIM + t];
    __syncthreads();

    const int cl = labels[n];
    const float ratio = *ratio_p;

    float s0 = score[n * 4 + 0], s1 = score[n * 4 + 1];
    float s2 = score[n * 4 + 2], s3 = score[n * 4 + 3];
    int ks = 0; float bs = s0;                   // strict <: first-min == jnp first-max
    if (s1 < bs) { bs = s1; ks = 1; }
    if (s2 < bs) { bs = s2; ks = 2; }
    if (s3 < bs) { bs = s3; ks = 3; }

    const int base = (cl * 4 + ks) * C_CLS;
    const float gll = gdiag[base + cl];
    float aug = -INFINITY;
    if (t < C_CLS) {
        const float4* wr = (const float4*)(weight + t * A_DIM);
        const float4* xr = (const float4*)xs;
        float acc = bias[t];
        #pragma unroll
        for (int j = 0; j < 32; ++j) {
            float4 a = xr[j], b = wr[j];
            acc += a.x * b.x + a.y * b.y + a.z * b.z + a.w * b.w;
        }
        y[(size_t)n * C_CLS + t] = acc;
        aug = acc + 0.5f * ratio * (gdiag[base + t] - 2.0f * gcol[base + t] + gll);
    }

    float m = aug;
    #pragma unroll
    for (int off = 32; off; off >>= 1) m = fmaxf(m, __shfl_xor(m, off, 64));
    if ((t & 63) == 0) red[t >> 6] = m;
    __syncthreads();
    m = fmaxf(red[0], red[1]);

    float e = (t < C_CLS) ? expf(aug - m) : 0.0f;
    #pragma unroll
    for (int off = 32; off; off >>= 1) e += __shfl_xor(e, off, 64);
    if ((t & 63) == 0) red2[t >> 6] = e;
    if (t == cl) acl_s = aug;
    __syncthreads();

    if (t == 0) {
        float sum = red2[0] + red2[1];
        float lp = acl_s - m - logf(sum);
        atomicAdd(loss, -lp * (1.0f / (float)N_S));
    }
}

// ---------------------------------------------------------------------------
extern "C" void kernel_launch(void* const* d_in, const int* in_sizes, int n_in,
                              void* d_out, int out_size, void* d_ws, size_t ws_size,
                              hipStream_t stream) {
    const float* features = (const float*)d_in[0];
    const float* weight   = (const float*)d_in[1];
    const float* bias     = (const float*)d_in[2];
    // d_in[3] = pi : unused (q is one-hot for any pi > 0; argmax unaffected)
    const float* mu       = (const float*)d_in[4];
    const float* sigma    = (const float*)d_in[5];
    const int*   labels   = (const int*)d_in[6];
    const float* ratio    = (const float*)d_in[7];

    float* out   = (float*)d_out;   // [0] = loss, [1..204800] = y
    float* yout  = out + 1;
    float* score = (float*)d_ws;                  // 8192 f32
    float* gdiag = score + N_S * K_CL;            // 40000 f32
    float* gcol  = gdiag + C_CLS * K_CL * C_CLS;  // 40000 f32
    int*   cntg  = (int*)(gcol + C_CLS * K_CL * C_CLS);  // 100 int
    int*   idxg  = cntg + C_CLS;                          // 100*96 int

    hipMemsetAsync(d_out, 0, sizeof(float), stream);   // zero the loss accumulator

    k_bucket      <<<dim3(1),            dim3(256), 0, stream>>>(labels, cntg, idxg);
    k_invert_score<<<dim3(C_CLS * K_CL), dim3(256), 0, stream>>>(sigma, mu, features, cntg, idxg, score);
    k_gprep       <<<dim3(C_CLS * K_CL), dim3(256), 0, stream>>>(sigma, weight, gdiag, gcol);
    k_out         <<<dim3(N_S),          dim3(128), 0, stream>>>(features, weight, bias, labels,
                                                                 score, gdiag, gcol, ratio, yout, out);
}

// Round 5
// 422.723 us; speedup vs baseline: 4.0639x; 4.0639x over previous
//
#include <hip/hip_runtime.h>
#include <hip/hip_bf16.h>
#include <cmath>

#define N_S    2048
#define C_CLS  100
#define K_CL   4
#define A_DIM  128
#define LDSROW 132   // 132*4=528B row stride: 16B-aligned rows, breaks 32-bank row aliasing
#define NB     16    // GJ panel width
#define MAXPER 96    // max samples per class (mean 20.5, this is >15 sigma)

// ---------------------------------------------------------------------------
// Kernel 0: bucket samples by class
// ---------------------------------------------------------------------------
__global__ __launch_bounds__(256) void k_bucket(
    const int* __restrict__ labels, int* __restrict__ cntg, int* __restrict__ idxg)
{
    __shared__ int cntL[C_CLS];
    const int t = threadIdx.x;
    if (t < C_CLS) cntL[t] = 0;
    __syncthreads();
    for (int n = t; n < N_S; n += 256) {
        int c = labels[n];
        int slot = atomicAdd(&cntL[c], 1);
        if (slot < MAXPER) idxg[c * MAXPER + slot] = n;
    }
    __syncthreads();
    if (t < C_CLS) cntg[t] = min(cntL[t], MAXPER);
}

// ---------------------------------------------------------------------------
// Kernel 1: per (cl,k) block: blocked Gauss-Jordan inversion of sigma[cl,k] in
// LDS (NB=16 panels; diagonal block inverted in-register by wave 0), fused
// logdet, then per-sample quadratic form for samples of class cl:
//   score[n][k] = (x-mu)^T Sigma^{-1} (x-mu) + logdet
// argmax_k log_p == argmin_k score.
// ---------------------------------------------------------------------------
__global__ __launch_bounds__(256, 2) void k_invert_score(
    const float* __restrict__ sigma, const float* __restrict__ mu,
    const float* __restrict__ features, const int* __restrict__ cntg,
    const int* __restrict__ idxg, float* __restrict__ score)
{
    __shared__ __align__(16) float As[A_DIM * LDSROW];
    __shared__ float DinvS[NB * 17];    // 17-stride: conflict-free row reads
    __shared__ float ldS;

    const int tid  = threadIdx.x;
    const int bid  = blockIdx.x;        // cl*K + k
    const int cl   = bid >> 2;
    const int lane = tid & 63;
    const int wv   = tid >> 6;

    // ---- stage sigma (coalesced b128) ----
    const float4* src = (const float4*)(sigma + (size_t)bid * A_DIM * A_DIM);
    for (int e4 = tid; e4 < A_DIM * 32; e4 += 256) {
        int i = e4 >> 5, j4 = e4 & 31;
        *(float4*)&As[i * LDSROW + 4 * j4] = src[e4];
    }
    __syncthreads();

    // ---- blocked GJ: 8 panels of 16 ----
    float logdet = 0.0f;                 // valid in wave 0 only
    const int rg  = tid >> 3;            // row group 0..31 (rows 4rg..4rg+3)
    const int cgr = tid & 7;             // col group (4 j4 = 16 cols) in update

    for (int t = 0; t < 8; ++t) {
        const int p0 = NB * t;

        // (a) wave 0: invert 16x16 diagonal block in registers
        if (wv == 0) {
            const int r = lane >> 2, cg = lane & 3;
            float4 dv = *(const float4*)&As[(p0 + r) * LDSROW + p0 + 4 * cg];
            #pragma unroll
            for (int p = 0; p < NB; ++p) {
                const int sel = p & 3, pr4 = p >> 2;
                float te = (sel == 0) ? dv.x : (sel == 1) ? dv.y : (sel == 2) ? dv.z : dv.w;
                float piv = __shfl(te, (p << 2) | pr4, 64);
                float ip  = 1.0f / piv;
                logdet += __logf(piv);
                const int rowsrc = (p << 2) | cg;
                float4 prs;
                prs.x = __shfl(dv.x, rowsrc, 64) * ip;
                prs.y = __shfl(dv.y, rowsrc, 64) * ip;
                prs.z = __shfl(dv.z, rowsrc, 64) * ip;
                prs.w = __shfl(dv.w, rowsrc, 64) * ip;
                if (cg == pr4) (&prs.x)[sel] = ip;           // row p, col p -> 1/piv
                float f = __shfl(te, (lane & ~3) | pr4, 64); // my row's col-p value
                if (r == p) {
                    dv = prs;
                } else {
                    dv.x -= f * prs.x; dv.y -= f * prs.y;
                    dv.z -= f * prs.z; dv.w -= f * prs.w;
                    if (cg == pr4) (&dv.x)[sel] = -f * ip;   // col p: assign
                }
            }
            DinvS[r * 17 + 4 * cg + 0] = dv.x;
            DinvS[r * 17 + 4 * cg + 1] = dv.y;
            DinvS[r * 17 + 4 * cg + 2] = dv.z;
            DinvS[r * 17 + 4 * cg + 3] = dv.w;
        }
        __syncthreads();   // b1: Dinv ready

        // (b) all: preload Cold (my 4 rows x 16 panel cols) into registers
        const bool inPanelR = ((rg >> 2) == t);
        float cold[4][NB];
        if (!inPanelR) {
            #pragma unroll
            for (int ri = 0; ri < 4; ++ri)
                #pragma unroll
                for (int k4 = 0; k4 < 4; ++k4) {
                    float4 v = *(const float4*)&As[(4 * rg + ri) * LDSROW + p0 + 4 * k4];
                    cold[ri][4 * k4 + 0] = v.x; cold[ri][4 * k4 + 1] = v.y;
                    cold[ri][4 * k4 + 2] = v.z; cold[ri][4 * k4 + 3] = v.w;
                }
        }
        // (c) row panel in place: Rnew = Dinv * A[P, j not in P]; A[P,P] = Dinv
        if (tid < 224) {
            const int q = tid >> 3, rr = tid & 7;
            const int j4 = (q < 4 * t) ? q : q + 4;     // skip the 4 panel j4s
            float4 s[NB];
            #pragma unroll
            for (int k = 0; k < NB; ++k)
                s[k] = *(const float4*)&As[(p0 + k) * LDSROW + 4 * j4];
            float4 o0 = {0, 0, 0, 0}, o1 = {0, 0, 0, 0};
            #pragma unroll
            for (int k = 0; k < NB; ++k) {
                float a0 = DinvS[(2 * rr) * 17 + k];
                float a1 = DinvS[(2 * rr + 1) * 17 + k];
                o0.x += a0 * s[k].x; o0.y += a0 * s[k].y; o0.z += a0 * s[k].z; o0.w += a0 * s[k].w;
                o1.x += a1 * s[k].x; o1.y += a1 * s[k].y; o1.z += a1 * s[k].z; o1.w += a1 * s[k].w;
            }
            // same-wave (8 threads/j4) ordering: all loads precede these stores
            *(float4*)&As[(p0 + 2 * rr)     * LDSROW + 4 * j4] = o0;
            *(float4*)&As[(p0 + 2 * rr + 1) * LDSROW + 4 * j4] = o1;
        } else {
            const int t2 = tid - 224, rD = t2 >> 1, hf = t2 & 1;
            float4 w0, w1;
            w0.x = DinvS[rD * 17 + 8 * hf + 0]; w0.y = DinvS[rD * 17 + 8 * hf + 1];
            w0.z = DinvS[rD * 17 + 8 * hf + 2]; w0.w = DinvS[rD * 17 + 8 * hf + 3];
            w1.x = DinvS[rD * 17 + 8 * hf + 4]; w1.y = DinvS[rD * 17 + 8 * hf + 5];
            w1.z = DinvS[rD * 17 + 8 * hf + 6]; w1.w = DinvS[rD * 17 + 8 * hf + 7];
            *(float4*)&As[(p0 + rD) * LDSROW + p0 + 8 * hf]     = w0;
            *(float4*)&As[(p0 + rD) * LDSROW + p0 + 8 * hf + 4] = w1;
        }
        __syncthreads();   // b2: row panel final

        // (d) rank-16 update of all non-panel rows (4 rows x 16 cols per thread)
        if (!inPanelR) {
            const bool pcol = (cgr == t);   // my 4 j4s are exactly the panel cols iff cgr==t
            float4 acc[4][4];
            #pragma unroll
            for (int ri = 0; ri < 4; ++ri)
                #pragma unroll
                for (int jj = 0; jj < 4; ++jj)
                    acc[ri][jj] = pcol ? (float4){0, 0, 0, 0}
                        : *(const float4*)&As[(4 * rg + ri) * LDSROW + 4 * (4 * cgr + jj)];
            #pragma unroll
            for (int k = 0; k < NB; ++k) {
                float4 rn[4];
                #pragma unroll
                for (int jj = 0; jj < 4; ++jj)
                    rn[jj] = *(const float4*)&As[(p0 + k) * LDSROW + 4 * (4 * cgr + jj)];
                #pragma unroll
                for (int ri = 0; ri < 4; ++ri) {
                    const float cf = cold[ri][k];
                    #pragma unroll
                    for (int jj = 0; jj < 4; ++jj) {
                        acc[ri][jj].x -= cf * rn[jj].x; acc[ri][jj].y -= cf * rn[jj].y;
                        acc[ri][jj].z -= cf * rn[jj].z; acc[ri][jj].w -= cf * rn[jj].w;
                    }
                }
            }
            #pragma unroll
            for (int ri = 0; ri < 4; ++ri)
                #pragma unroll
                for (int jj = 0; jj < 4; ++jj)
                    *(float4*)&As[(4 * rg + ri) * LDSROW + 4 * (4 * cgr + jj)] = acc[ri][jj];
        }
        __syncthreads();   // b3: panel done
    }
    // As = Sigma^{-1}

    if (tid == 0) ldS = logdet;
    __syncthreads();
    const float ld = ldS;

    // ---- per-sample quadratic form (bucketed; one sample per wave) ----
    const float m0 = mu[(size_t)bid * A_DIM + lane];
    const float m1 = mu[(size_t)bid * A_DIM + 64 + lane];
    const int cnt = cntg[cl];
    for (int s = wv; s < cnt; s += 4) {
        const int n = idxg[cl * MAXPER + s];
        float d0 = features[(size_t)n * A_DIM + lane]      - m0;
        float d1 = features[(size_t)n * A_DIM + 64 + lane] - m1;
        float p0v = 0.f, p1v = 0.f;
        for (int i = 0; i < 64; ++i) {
            float b = __shfl(d0, i, 64);
            p0v += b * As[i * LDSROW + lane];
            p1v += b * As[i * LDSROW + 64 + lane];
        }
        for (int i = 0; i < 64; ++i) {
            float b = __shfl(d1, i, 64);
            p0v += b * As[(i + 64) * LDSROW + lane];
            p1v += b * As[(i + 64) * LDSROW + 64 + lane];
        }
        float q = d0 * p0v + d1 * p1v;
        #pragma unroll
        for (int off = 32; off; off >>= 1) q += __shfl_xor(q, off, 64);
        if (lane == 0) score[n * K_CL + (bid & 3)] = q + ld;
    }
}

// ---------------------------------------------------------------------------
// Kernel 2: per (cl,k): gdiag[c]=W[c] S W[c]^T, gcol[c]=W[c] S W[cl]^T
// No per-thread arrays, no shfl: W staged in LDS, W[c,i] read as same-address
// LDS broadcast (free); 5 rows batched with NAMED scalar accumulators so
// nothing can be demoted to scratch (round-3 lesson: 1.9GB scratch traffic).
// Sigma unpadded: all Ss accesses are row-contiguous (conflict-free).
// ---------------------------------------------------------------------------
__global__ __launch_bounds__(256) void k_gprep(
    const float* __restrict__ sigma, const float* __restrict__ weight,
    float* __restrict__ gdiag, float* __restrict__ gcol)
{
    __shared__ __align__(16) float Ss[A_DIM * A_DIM];   // 64 KB
    __shared__ __align__(16) float Ws[C_CLS * A_DIM];   // 51.2 KB
    const int tid = threadIdx.x, bid = blockIdx.x;
    const int cl  = bid >> 2;
    const int lane = tid & 63, wv = tid >> 6;

    const float4* src = (const float4*)(sigma + (size_t)bid * A_DIM * A_DIM);
    for (int e4 = tid; e4 < A_DIM * 32; e4 += 256)
        ((float4*)Ss)[e4] = src[e4];
    const float4* wsrc = (const float4*)weight;
    for (int e4 = tid; e4 < C_CLS * 32; e4 += 256)
        ((float4*)Ws)[e4] = wsrc[e4];
    __syncthreads();

    const float wc0 = Ws[cl * A_DIM + lane];
    const float wc1 = Ws[cl * A_DIM + 64 + lane];
    const int cbeg = wv * 25;               // 4 waves x 25 classes = 100

    for (int g = 0; g < 5; ++g) {           // 5 uniform groups of 5 rows
        const int c0 = cbeg + g * 5;
        const float* w0 = &Ws[(c0 + 0) * A_DIM];
        const float* w1 = &Ws[(c0 + 1) * A_DIM];
        const float* w2 = &Ws[(c0 + 2) * A_DIM];
        const float* w3 = &Ws[(c0 + 3) * A_DIM];
        const float* w4 = &Ws[(c0 + 4) * A_DIM];
        float h00 = 0.f, h01 = 0.f, h02 = 0.f, h03 = 0.f, h04 = 0.f;  // j = lane
        float h10 = 0.f, h11 = 0.f, h12 = 0.f, h13 = 0.f, h14 = 0.f;  // j = lane+64
        #pragma unroll 4
        for (int i = 0; i < A_DIM; ++i) {
            const float s0 = Ss[i * A_DIM + lane];
            const float s1 = Ss[i * A_DIM + 64 + lane];
            const float b0 = w0[i], b1 = w1[i], b2 = w2[i], b3 = w3[i], b4 = w4[i];
            h00 += b0 * s0; h10 += b0 * s1;
            h01 += b1 * s0; h11 += b1 * s1;
            h02 += b2 * s0; h12 += b2 * s1;
            h03 += b3 * s0; h13 += b3 * s1;
            h04 += b4 * s0; h14 += b4 * s1;
        }
        #define GOUT(HA, HB, CC)                                            \
        {                                                                   \
            const int c = c0 + (CC);                                        \
            float pd = (HA) * Ws[c * A_DIM + lane]                          \
                     + (HB) * Ws[c * A_DIM + 64 + lane];                    \
            float pc = (HA) * wc0 + (HB) * wc1;                             \
            _Pragma("unroll")                                               \
            for (int off = 32; off; off >>= 1) {                            \
                pd += __shfl_xor(pd, off, 64);                              \
                pc += __shfl_xor(pc, off, 64);                              \
            }                                                               \
            if (lane == 0) {                                                \
                gdiag[bid * C_CLS + c] = pd;                                \
                gcol [bid * C_CLS + c] = pc;                                \
            }                                                               \
        }
        GOUT(h00, h10, 0)
        GOUT(h01, h11, 1)
        GOUT(h02, h12, 2)
        GOUT(h03, h13, 3)
        GOUT(h04, h14, 4)
        #undef GOUT
    }
}

// ---------------------------------------------------------------------------
// Kernel 3 (fused fc + final): per sample: y = xW^T+b (written out), kstar =
// argmin_k score, aug = y + 0.5*ratio*(gdiag - 2 gcol + gll), log-softmax, loss.
// ---------------------------------------------------------------------------
__global__ __launch_bounds__(128) void k_out(
    const float* __restrict__ features, const float* __restrict__ weight,
    const float* __restrict__ bias, const int* __restrict__ labels,
    const float* __restrict__ score, const float* __restrict__ gdiag,
    const float* __restrict__ gcol, const float* __restrict__ ratio_p,
    float* __restrict__ y, float* __restrict__ loss)
{
    __shared__ __align__(16) float xs[A_DIM];
    __shared__ float red[2], red2[2], acl_s;
    const int n = blockIdx.x, t = threadIdx.x;
    xs[t] = features[(size_t)n * A_DIM + t];
    __syncthreads();

    const int cl = labels[n];
    const float ratio = *ratio_p;

    float s0 = score[n * 4 + 0], s1 = score[n * 4 + 1];
    float s2 = score[n * 4 + 2], s3 = score[n * 4 + 3];
    int ks = 0; float bs = s0;                   // strict <: first-min == jnp first-max
    if (s1 < bs) { bs = s1; ks = 1; }
    if (s2 < bs) { bs = s2; ks = 2; }
    if (s3 < bs) { bs = s3; ks = 3; }

    const int base = (cl * 4 + ks) * C_CLS;
    const float gll = gdiag[base + cl];
    float aug = -INFINITY;
    if (t < C_CLS) {
        const float4* wr = (const float4*)(weight + t * A_DIM);
        const float4* xr = (const float4*)xs;
        float acc = bias[t];
        #pragma unroll
        for (int j = 0; j < 32; ++j) {
            float4 a = xr[j], b = wr[j];
            acc += a.x * b.x + a.y * b.y + a.z * b.z + a.w * b.w;
        }
        y[(size_t)n * C_CLS + t] = acc;
        aug = acc + 0.5f * ratio * (gdiag[base + t] - 2.0f * gcol[base + t] + gll);
    }

    float m = aug;
    #pragma unroll
    for (int off = 32; off; off >>= 1) m = fmaxf(m, __shfl_xor(m, off, 64));
    if ((t & 63) == 0) red[t >> 6] = m;
    __syncthreads();
    m = fmaxf(red[0], red[1]);

    float e = (t < C_CLS) ? expf(aug - m) : 0.0f;
    #pragma unroll
    for (int off = 32; off; off >>= 1) e += __shfl_xor(e, off, 64);
    if ((t & 63) == 0) red2[t >> 6] = e;
    if (t == cl) acl_s = aug;
    __syncthreads();

    if (t == 0) {
        float sum = red2[0] + red2[1];
        float lp = acl_s - m - logf(sum);
        atomicAdd(loss, -lp * (1.0f / (float)N_S));
    }
}

// ---------------------------------------------------------------------------
extern "C" void kernel_launch(void* const* d_in, const int* in_sizes, int n_in,
                              void* d_out, int out_size, void* d_ws, size_t ws_size,
                              hipStream_t stream) {
    const float* features = (const float*)d_in[0];
    const float* weight   = (const float*)d_in[1];
    const float* bias     = (const float*)d_in[2];
    // d_in[3] = pi : unused (q is one-hot for any pi > 0; argmax unaffected)
    const float* mu       = (const float*)d_in[4];
    const float* sigma    = (const float*)d_in[5];
    const int*   labels   = (const int*)d_in[6];
    const float* ratio    = (const float*)d_in[7];

    float* out   = (float*)d_out;   // [0] = loss, [1..204800] = y
    float* yout  = out + 1;
    float* score = (float*)d_ws;                  // 8192 f32
    float* gdiag = score + N_S * K_CL;            // 40000 f32
    float* gcol  = gdiag + C_CLS * K_CL * C_CLS;  // 40000 f32
    int*   cntg  = (int*)(gcol + C_CLS * K_CL * C_CLS);  // 100 int
    int*   idxg  = cntg + C_CLS;                          // 100*96 int

    hipMemsetAsync(d_out, 0, sizeof(float), stream);   // zero the loss accumulator

    k_bucket      <<<dim3(1),            dim3(256), 0, stream>>>(labels, cntg, idxg);
    k_invert_score<<<dim3(C_CLS * K_CL), dim3(256), 0, stream>>>(sigma, mu, features, cntg, idxg, score);
    k_gprep       <<<dim3(C_CLS * K_CL), dim3(256), 0, stream>>>(sigma, weight, gdiag, gcol);
    k_out         <<<dim3(N_S),          dim3(128), 0, stream>>>(features, weight, bias, labels,
                                                                 score, gdiag, gcol, ratio, yout, out);
}

// Round 6
// 361.149 us; speedup vs baseline: 4.7568x; 1.1705x over previous
//
#include <hip/hip_runtime.h>
#include <hip/hip_bf16.h>
#include <cmath>

#define N_S    2048
#define C_CLS  100
#define K_CL   4
#define A_DIM  128
#define LDSROW 132   // padded row stride: breaks row-power-of-2 bank aliasing
#define NB     16    // GJ panel width
#define MAXPER 96    // max samples per class (mean 20.5; >15 sigma headroom)

// ---------------------------------------------------------------------------
// Kernel 0: bucket samples by class
// ---------------------------------------------------------------------------
__global__ __launch_bounds__(256) void k_bucket(
    const int* __restrict__ labels, int* __restrict__ cntg, int* __restrict__ idxg)
{
    __shared__ int cntL[C_CLS];
    const int t = threadIdx.x;
    if (t < C_CLS) cntL[t] = 0;
    __syncthreads();
    for (int n = t; n < N_S; n += 256) {
        int c = labels[n];
        int slot = atomicAdd(&cntL[c], 1);
        if (slot < MAXPER) idxg[c * MAXPER + slot] = n;
    }
    __syncthreads();
    if (t < C_CLS) cntg[t] = min(cntL[t], MAXPER);
}

// ---------------------------------------------------------------------------
// Kernel 1 (REWRITTEN, 512 thr): blocked GJ inverse of sigma[cl,k] in LDS.
// Round-5 lesson: cold[4][16]+s[16]+acc[4][4] register tiles spilled ->
// 147MB scratch round-trip. Now: row-panel goes through an LDS bounce buffer
// (no s[16]), cold is read on-the-fly as LDS broadcasts (no cold[] array),
// per-thread update tile is 4x8 (acc=32 VGPR). Peak live regs ~60.
// Then fused per-sample quadratic form: score = (x-mu)^T Sinv (x-mu) + logdet.
// ---------------------------------------------------------------------------
__global__ __launch_bounds__(512, 2) void k_invert_score(
    const float* __restrict__ sigma, const float* __restrict__ mu,
    const float* __restrict__ features, const int* __restrict__ cntg,
    const int* __restrict__ idxg, float* __restrict__ score)
{
    __shared__ __align__(16) float As[A_DIM * LDSROW];   // 67.6 KB
    __shared__ __align__(16) float Rbuf[NB * A_DIM];     // 8.2 KB
    __shared__ float DinvS[NB * 17];                     // conflict-free rows
    __shared__ float ldS;

    const int tid  = threadIdx.x;
    const int bid  = blockIdx.x;        // cl*K_CL + k
    const int cl   = bid >> 2;
    const int lane = tid & 63;
    const int wv   = tid >> 6;

    // ---- stage sigma (coalesced b128) ----
    const float4* src = (const float4*)(sigma + (size_t)bid * A_DIM * A_DIM);
    for (int e4 = tid; e4 < A_DIM * 32; e4 += 512) {
        int i = e4 >> 5, j4 = e4 & 31;
        *(float4*)&As[i * LDSROW + 4 * j4] = src[e4];
    }
    __syncthreads();

    float logdet = 0.0f;                 // valid in wave 0 only

    for (int t = 0; t < 8; ++t) {
        const int p0 = NB * t;

        // (a) wave 0: invert 16x16 diagonal block in registers (shfl GJ)
        if (wv == 0) {
            const int r = lane >> 2, cg = lane & 3;
            float4 dv = *(const float4*)&As[(p0 + r) * LDSROW + p0 + 4 * cg];
            #pragma unroll
            for (int p = 0; p < NB; ++p) {
                const int sel = p & 3, pr4 = p >> 2;
                float te = (sel == 0) ? dv.x : (sel == 1) ? dv.y : (sel == 2) ? dv.z : dv.w;
                float piv = __shfl(te, (p << 2) | pr4, 64);
                float ip  = 1.0f / piv;
                logdet += __logf(piv);
                const int rowsrc = (p << 2) | cg;
                float4 prs;
                prs.x = __shfl(dv.x, rowsrc, 64) * ip;
                prs.y = __shfl(dv.y, rowsrc, 64) * ip;
                prs.z = __shfl(dv.z, rowsrc, 64) * ip;
                prs.w = __shfl(dv.w, rowsrc, 64) * ip;
                if (cg == pr4) (&prs.x)[sel] = ip;           // (p,p) -> 1/piv
                float f = __shfl(te, (lane & ~3) | pr4, 64); // my row's col-p value
                if (r == p) {
                    dv = prs;
                } else {
                    dv.x -= f * prs.x; dv.y -= f * prs.y;
                    dv.z -= f * prs.z; dv.w -= f * prs.w;
                    if (cg == pr4) (&dv.x)[sel] = -f * ip;   // col p: assign
                }
            }
            DinvS[r * 17 + 4 * cg + 0] = dv.x;
            DinvS[r * 17 + 4 * cg + 1] = dv.y;
            DinvS[r * 17 + 4 * cg + 2] = dv.z;
            DinvS[r * 17 + 4 * cg + 3] = dv.w;
        }
        __syncthreads();   // b1: Dinv ready

        // (b) Rnew = Dinv * A[P,:] into Rbuf; panel cols get Dinv itself.
        // 512 threads: one float4 each (row rr, col quad j4c). Accumulate
        // straight from LDS: no register staging.
        {
            const int rr = tid >> 5, j4c = tid & 31;
            float4 o;
            if ((j4c >> 2) == t) {
                const int cg = j4c & 3;
                o.x = DinvS[rr * 17 + 4 * cg + 0];
                o.y = DinvS[rr * 17 + 4 * cg + 1];
                o.z = DinvS[rr * 17 + 4 * cg + 2];
                o.w = DinvS[rr * 17 + 4 * cg + 3];
            } else {
                o.x = 0.f; o.y = 0.f; o.z = 0.f; o.w = 0.f;
                #pragma unroll
                for (int k = 0; k < NB; ++k) {
                    const float a = DinvS[rr * 17 + k];          // 2-addr broadcast
                    const float4 s4 = *(const float4*)&As[(p0 + k) * LDSROW + 4 * j4c];
                    o.x += a * s4.x; o.y += a * s4.y; o.z += a * s4.z; o.w += a * s4.w;
                }
            }
            *(float4*)&Rbuf[rr * A_DIM + 4 * j4c] = o;
        }
        __syncthreads();   // b2: Rnew ready (As panel rows still OLD)

        // (c) rank-16 update of 112 non-panel rows: per thread 4 rows x 8 cols.
        // cold (panel cols of my rows) read on-the-fly: 16-lane broadcast, and
        // all reads precede the acc stores (same-wave row groups; data dep).
        if (tid < 448) {
            const int rgi = tid >> 4;                 // 0..27 non-panel row group
            const int cp  = tid & 15;                 // j4 pair
            const int rga = (rgi < 4 * t) ? rgi : rgi + 4;
            const int row0 = 4 * rga;
            const int c0 = 8 * cp, c1 = 8 * cp + 4;
            const bool pcol = ((cp >> 1) == t);       // my 2 j4s are the panel cols
            float4 a00, a01, a10, a11, a20, a21, a30, a31;
            if (pcol) {
                a00 = a01 = a10 = a11 = a20 = a21 = a30 = a31 = (float4){0, 0, 0, 0};
            } else {
                a00 = *(const float4*)&As[(row0 + 0) * LDSROW + c0];
                a01 = *(const float4*)&As[(row0 + 0) * LDSROW + c1];
                a10 = *(const float4*)&As[(row0 + 1) * LDSROW + c0];
                a11 = *(const float4*)&As[(row0 + 1) * LDSROW + c1];
                a20 = *(const float4*)&As[(row0 + 2) * LDSROW + c0];
                a21 = *(const float4*)&As[(row0 + 2) * LDSROW + c1];
                a30 = *(const float4*)&As[(row0 + 3) * LDSROW + c0];
                a31 = *(const float4*)&As[(row0 + 3) * LDSROW + c1];
            }
            #pragma unroll
            for (int k = 0; k < NB; ++k) {
                const float4 r0 = *(const float4*)&Rbuf[k * A_DIM + c0];
                const float4 r1 = *(const float4*)&Rbuf[k * A_DIM + c1];
                const float f0 = As[(row0 + 0) * LDSROW + p0 + k];
                const float f1 = As[(row0 + 1) * LDSROW + p0 + k];
                const float f2 = As[(row0 + 2) * LDSROW + p0 + k];
                const float f3 = As[(row0 + 3) * LDSROW + p0 + k];
                a00.x -= f0 * r0.x; a00.y -= f0 * r0.y; a00.z -= f0 * r0.z; a00.w -= f0 * r0.w;
                a01.x -= f0 * r1.x; a01.y -= f0 * r1.y; a01.z -= f0 * r1.z; a01.w -= f0 * r1.w;
                a10.x -= f1 * r0.x; a10.y -= f1 * r0.y; a10.z -= f1 * r0.z; a10.w -= f1 * r0.w;
                a11.x -= f1 * r1.x; a11.y -= f1 * r1.y; a11.z -= f1 * r1.z; a11.w -= f1 * r1.w;
                a20.x -= f2 * r0.x; a20.y -= f2 * r0.y; a20.z -= f2 * r0.z; a20.w -= f2 * r0.w;
                a21.x -= f2 * r1.x; a21.y -= f2 * r1.y; a21.z -= f2 * r1.z; a21.w -= f2 * r1.w;
                a30.x -= f3 * r0.x; a30.y -= f3 * r0.y; a30.z -= f3 * r0.z; a30.w -= f3 * r0.w;
                a31.x -= f3 * r1.x; a31.y -= f3 * r1.y; a31.z -= f3 * r1.z; a31.w -= f3 * r1.w;
            }
            *(float4*)&As[(row0 + 0) * LDSROW + c0] = a00;
            *(float4*)&As[(row0 + 0) * LDSROW + c1] = a01;
            *(float4*)&As[(row0 + 1) * LDSROW + c0] = a10;
            *(float4*)&As[(row0 + 1) * LDSROW + c1] = a11;
            *(float4*)&As[(row0 + 2) * LDSROW + c0] = a20;
            *(float4*)&As[(row0 + 2) * LDSROW + c1] = a21;
            *(float4*)&As[(row0 + 3) * LDSROW + c0] = a30;
            *(float4*)&As[(row0 + 3) * LDSROW + c1] = a31;
        }
        // copyback Rbuf -> As panel rows (writes panel rows only; update reads
        // touch non-panel rows + Rbuf, so no conflict)
        {
            const int rr = tid >> 5, j4c = tid & 31;
            *(float4*)&As[(p0 + rr) * LDSROW + 4 * j4c] =
                *(const float4*)&Rbuf[rr * A_DIM + 4 * j4c];
        }
        __syncthreads();   // b3: panel done
    }
    // As = Sigma^{-1}

    if (tid == 0) ldS = logdet;
    __syncthreads();
    const float ld = ldS;

    // ---- per-sample quadratic form (bucketed; one sample per wave) ----
    const float m0 = mu[(size_t)bid * A_DIM + lane];
    const float m1 = mu[(size_t)bid * A_DIM + 64 + lane];
    const int cnt = cntg[cl];
    for (int s = wv; s < cnt; s += 8) {
        const int n = idxg[cl * MAXPER + s];
        float d0 = features[(size_t)n * A_DIM + lane]      - m0;
        float d1 = features[(size_t)n * A_DIM + 64 + lane] - m1;
        float p0v = 0.f, p1v = 0.f;
        for (int i = 0; i < 64; ++i) {
            float b = __shfl(d0, i, 64);
            p0v += b * As[i * LDSROW + lane];
            p1v += b * As[i * LDSROW + 64 + lane];
        }
        for (int i = 0; i < 64; ++i) {
            float b = __shfl(d1, i, 64);
            p0v += b * As[(i + 64) * LDSROW + lane];
            p1v += b * As[(i + 64) * LDSROW + 64 + lane];
        }
        float q = d0 * p0v + d1 * p1v;
        #pragma unroll
        for (int off = 32; off; off >>= 1) q += __shfl_xor(q, off, 64);
        if (lane == 0) score[n * K_CL + (bid & 3)] = q + ld;
    }
}

// ---------------------------------------------------------------------------
// Kernel 2: per (cl,k): gdiag[c]=W[c] S W[c]^T, gcol[c]=W[c] S W[cl]^T
// (named scalar accumulators; LDS-broadcast W reads; unchanged from round 5)
// ---------------------------------------------------------------------------
__global__ __launch_bounds__(256) void k_gprep(
    const float* __restrict__ sigma, const float* __restrict__ weight,
    float* __restrict__ gdiag, float* __restrict__ gcol)
{
    __shared__ __align__(16) float Ss[A_DIM * A_DIM];   // 64 KB
    __shared__ __align__(16) float Ws[C_CLS * A_DIM];   // 51.2 KB
    const int tid = threadIdx.x, bid = blockIdx.x;
    const int cl  = bid >> 2;
    const int lane = tid & 63, wv = tid >> 6;

    const float4* src = (const float4*)(sigma + (size_t)bid * A_DIM * A_DIM);
    for (int e4 = tid; e4 < A_DIM * 32; e4 += 256)
        ((float4*)Ss)[e4] = src[e4];
    const float4* wsrc = (const float4*)weight;
    for (int e4 = tid; e4 < C_CLS * 32; e4 += 256)
        ((float4*)Ws)[e4] = wsrc[e4];
    __syncthreads();

    const float wc0 = Ws[cl * A_DIM + lane];
    const float wc1 = Ws[cl * A_DIM + 64 + lane];
    const int cbeg = wv * 25;               // 4 waves x 25 classes = 100

    for (int g = 0; g < 5; ++g) {           // 5 uniform groups of 5 rows
        const int c0 = cbeg + g * 5;
        const float* w0 = &Ws[(c0 + 0) * A_DIM];
        const float* w1 = &Ws[(c0 + 1) * A_DIM];
        const float* w2 = &Ws[(c0 + 2) * A_DIM];
        const float* w3 = &Ws[(c0 + 3) * A_DIM];
        const float* w4 = &Ws[(c0 + 4) * A_DIM];
        float h00 = 0.f, h01 = 0.f, h02 = 0.f, h03 = 0.f, h04 = 0.f;  // j = lane
        float h10 = 0.f, h11 = 0.f, h12 = 0.f, h13 = 0.f, h14 = 0.f;  // j = lane+64
        #pragma unroll 4
        for (int i = 0; i < A_DIM; ++i) {
            const float s0 = Ss[i * A_DIM + lane];
            const float s1 = Ss[i * A_DIM + 64 + lane];
            const float b0 = w0[i], b1 = w1[i], b2 = w2[i], b3 = w3[i], b4 = w4[i];
            h00 += b0 * s0; h10 += b0 * s1;
            h01 += b1 * s0; h11 += b1 * s1;
            h02 += b2 * s0; h12 += b2 * s1;
            h03 += b3 * s0; h13 += b3 * s1;
            h04 += b4 * s0; h14 += b4 * s1;
        }
        #define GOUT(HA, HB, CC)                                            \
        {                                                                   \
            const int c = c0 + (CC);                                        \
            float pd = (HA) * Ws[c * A_DIM + lane]                          \
                     + (HB) * Ws[c * A_DIM + 64 + lane];                    \
            float pc = (HA) * wc0 + (HB) * wc1;                             \
            _Pragma("unroll")                                               \
            for (int off = 32; off; off >>= 1) {                            \
                pd += __shfl_xor(pd, off, 64);                              \
                pc += __shfl_xor(pc, off, 64);                              \
            }                                                               \
            if (lane == 0) {                                                \
                gdiag[bid * C_CLS + c] = pd;                                \
                gcol [bid * C_CLS + c] = pc;                                \
            }                                                               \
        }
        GOUT(h00, h10, 0)
        GOUT(h01, h11, 1)
        GOUT(h02, h12, 2)
        GOUT(h03, h13, 3)
        GOUT(h04, h14, 4)
        #undef GOUT
    }
}

// ---------------------------------------------------------------------------
// Kernel 3 (fused fc + final)
// ---------------------------------------------------------------------------
__global__ __launch_bounds__(128) void k_out(
    const float* __restrict__ features, const float* __restrict__ weight,
    const float* __restrict__ bias, const int* __restrict__ labels,
    const float* __restrict__ score, const float* __restrict__ gdiag,
    const float* __restrict__ gcol, const float* __restrict__ ratio_p,
    float* __restrict__ y, float* __restrict__ loss)
{
    __shared__ __align__(16) float xs[A_DIM];
    __shared__ float red[2], red2[2], acl_s;
    const int n = blockIdx.x, t = threadIdx.x;
    xs[t] = features[(size_t)n * A_DIM + t];
    __syncthreads();

    const int cl = labels[n];
    const float ratio = *ratio_p;

    float s0 = score[n * 4 + 0], s1 = score[n * 4 + 1];
    float s2 = score[n * 4 + 2], s3 = score[n * 4 + 3];
    int ks = 0; float bs = s0;                   // strict <: first-min == jnp first-max
    if (s1 < bs) { bs = s1; ks = 1; }
    if (s2 < bs) { bs = s2; ks = 2; }
    if (s3 < bs) { bs = s3; ks = 3; }

    const int base = (cl * 4 + ks) * C_CLS;
    const float gll = gdiag[base + cl];
    float aug = -INFINITY;
    if (t < C_CLS) {
        const float4* wr = (const float4*)(weight + t * A_DIM);
        const float4* xr = (const float4*)xs;
        float acc = bias[t];
        #pragma unroll
        for (int j = 0; j < 32; ++j) {
            float4 a = xr[j], b = wr[j];
            acc += a.x * b.x + a.y * b.y + a.z * b.z + a.w * b.w;
        }
        y[(size_t)n * C_CLS + t] = acc;
        aug = acc + 0.5f * ratio * (gdiag[base + t] - 2.0f * gcol[base + t] + gll);
    }

    float m = aug;
    #pragma unroll
    for (int off = 32; off; off >>= 1) m = fmaxf(m, __shfl_xor(m, off, 64));
    if ((t & 63) == 0) red[t >> 6] = m;
    __syncthreads();
    m = fmaxf(red[0], red[1]);

    float e = (t < C_CLS) ? expf(aug - m) : 0.0f;
    #pragma unroll
    for (int off = 32; off; off >>= 1) e += __shfl_xor(e, off, 64);
    if ((t & 63) == 0) red2[t >> 6] = e;
    if (t == cl) acl_s = aug;
    __syncthreads();

    if (t == 0) {
        float sum = red2[0] + red2[1];
        float lp = acl_s - m - logf(sum);
        atomicAdd(loss, -lp * (1.0f / (float)N_S));
    }
}

// ---------------------------------------------------------------------------
extern "C" void kernel_launch(void* const* d_in, const int* in_sizes, int n_in,
                              void* d_out, int out_size, void* d_ws, size_t ws_size,
                              hipStream_t stream) {
    const float* features = (const float*)d_in[0];
    const float* weight   = (const float*)d_in[1];
    const float* bias     = (const float*)d_in[2];
    // d_in[3] = pi : unused (q is one-hot for any pi > 0; argmax unaffected)
    const float* mu       = (const float*)d_in[4];
    const float* sigma    = (const float*)d_in[5];
    const int*   labels   = (const int*)d_in[6];
    const float* ratio    = (const float*)d_in[7];

    float* out   = (float*)d_out;   // [0] = loss, [1..204800] = y
    float* yout  = out + 1;
    float* score = (float*)d_ws;                  // 8192 f32
    float* gdiag = score + N_S * K_CL;            // 40000 f32
    float* gcol  = gdiag + C_CLS * K_CL * C_CLS;  // 40000 f32
    int*   cntg  = (int*)(gcol + C_CLS * K_CL * C_CLS);  // 100 int
    int*   idxg  = cntg + C_CLS;                          // 100*96 int

    hipMemsetAsync(d_out, 0, sizeof(float), stream);   // zero the loss accumulator

    k_bucket      <<<dim3(1),            dim3(256), 0, stream>>>(labels, cntg, idxg);
    k_invert_score<<<dim3(C_CLS * K_CL), dim3(512), 0, stream>>>(sigma, mu, features, cntg, idxg, score);
    k_gprep       <<<dim3(C_CLS * K_CL), dim3(256), 0, stream>>>(sigma, weight, gdiag, gcol);
    k_out         <<<dim3(N_S),          dim3(128), 0, stream>>>(features, weight, bias, labels,
                                                                 score, gdiag, gcol, ratio, yout, out);
}